// Round 15
// baseline (190.619 us; speedup 1.0000x reference)
//
#include <hip/hip_runtime.h>
#include <hip/hip_bf16.h>

typedef unsigned short u16;
typedef __bf16 bf16x8 __attribute__((ext_vector_type(8)));
typedef float f32x4 __attribute__((ext_vector_type(4)));

#define AS1 __attribute__((address_space(1)))
#define AS3 __attribute__((address_space(3)))

__device__ __forceinline__ u16 f2bf(float f) {
  unsigned u = __builtin_bit_cast(unsigned, f);
  u += 0x7FFFu + ((u >> 16) & 1u);
  return (u16)(u >> 16);
}

__device__ __forceinline__ void gload_lds16(const void* g, void* l) {
  __builtin_amdgcn_global_load_lds((AS1 void*)g, (AS3 void*)l, 16, 0, 0);
}

// ---------------- unified conversion: x + weights + bias, ONE launch --------
__global__ __launch_bounds__(256)
void cvt_all(const float* __restrict__ x,
             const float* __restrict__ Wq, const float* __restrict__ Wk,
             const float* __restrict__ Wv, const float* __restrict__ Wo,
             const float* __restrict__ bq, const float* __restrict__ bk,
             const float* __restrict__ bv,
             u16* __restrict__ xb, u16* __restrict__ wqkv, u16* __restrict__ wo,
             float* __restrict__ bias_a, float qs) {
  const long NX = 1048576, NQ = 524288, NK = 32768, NV = 32768, NO = 524288;
  const long NW = NX + NQ + NK + NV + NO;
  long i = (long)blockIdx.x * 256 + threadIdx.x;
  if (i >= NW) {  // bias tail
    int t = (int)(i - NW);
    if (t < 2048) bias_a[t] = bq[t] * qs;
    else if (t < 2176) bias_a[t] = bk[t - 2048];
    else if (t < 2304) bias_a[t] = bv[t - 2176];
    return;
  }
  const float* src;
  u16* dst;
  float s = 1.f;
  if (i < NX) { src = x + i * 8; dst = xb + i * 8; }
  else if (i < NX + NQ) { long j = i - NX; src = Wq + j * 8; dst = wqkv + j * 8; s = qs; }
  else if (i < NX + NQ + NK) { long j = i - NX - NQ; src = Wk + j * 8; dst = wqkv + 2048l * 2048 + j * 8; }
  else if (i < NX + NQ + NK + NV) { long j = i - NX - NQ - NK; src = Wv + j * 8; dst = wqkv + 2176l * 2048 + j * 8; }
  else { long j = i - NX - NQ - NK - NV; src = Wo + j * 8; dst = wo + j * 8; }
  float4 a = *(const float4*)src;
  float4 b = *(const float4*)(src + 4);
  u16 t[8] = {f2bf(a.x * s), f2bf(a.y * s), f2bf(a.z * s), f2bf(a.w * s),
              f2bf(b.x * s), f2bf(b.y * s), f2bf(b.z * s), f2bf(b.w * s)};
  *(uint4*)dst = *(const uint4*)t;
}

// ---------------- GEMM: C = (A @ B^T + bias) * scale ----------------
// R14-verified: BK=64, XOR-swizzled LDS (src pre-swizzled, reads same XOR).
template<int MODE>
__global__ __launch_bounds__(256)
void gemm_bt(const u16* __restrict__ A, const u16* __restrict__ B,
             const float* __restrict__ bias, void* __restrict__ C0,
             void* __restrict__ C1, void* __restrict__ C2,
             int M, int N, int K, float scale)
{
  __shared__ u16 As[128 * 64];
  __shared__ u16 Bs[128 * 64];
  const int tid = threadIdx.x;
  const int wave = tid >> 6, lane = tid & 63;
  const int g = lane >> 4, r = lane & 15;
  const int wrow = (wave >> 1) * 64, wcol = (wave & 1) * 64;

  const int gx = gridDim.x;
  int lin = blockIdx.y * gx + blockIdx.x;
  const int cpx = (gx * gridDim.y) >> 3;
  lin = (lin & 7) * cpx + (lin >> 3);
  const long tM = (long)(lin / gx) * 128, tN = (long)(lin % gx) * 128;

  const int srow = (tid * 16) >> 7;
  const int scol = (tid & 7) * 8;

  f32x4 acc[4][4] = {};
  char* As3 = (char*)As;
  char* Bs3 = (char*)Bs;

  for (int kt = 0; kt < K; kt += 64) {
    __syncthreads();
#pragma unroll
    for (int p = 0; p < 4; p++) {
      const int row = p * 32 + srow;
      const int sc = scol ^ ((row & 7) << 3);
      gload_lds16(A + (tM + row) * K + kt + sc, As3 + p * 4096 + tid * 16);
      gload_lds16(B + (tN + row) * K + kt + sc, Bs3 + p * 4096 + tid * 16);
    }
    __syncthreads();

#pragma unroll
    for (int kk = 0; kk < 2; kk++) {
      bf16x8 a[4], b[4];
#pragma unroll
      for (int m = 0; m < 4; m++) {
        const int ra = wrow + m * 16 + r;
        a[m] = *(const bf16x8*)(As + ra * 64 + ((kk * 32 + g * 8) ^ ((ra & 7) << 3)));
      }
#pragma unroll
      for (int n = 0; n < 4; n++) {
        const int rb = wcol + n * 16 + r;
        b[n] = *(const bf16x8*)(Bs + rb * 64 + ((kk * 32 + g * 8) ^ ((rb & 7) << 3)));
      }
#pragma unroll
      for (int m = 0; m < 4; m++)
#pragma unroll
        for (int n = 0; n < 4; n++)
          acc[m][n] = __builtin_amdgcn_mfma_f32_16x16x32_bf16(a[m], b[n], acc[m][n], 0, 0, 0);
    }
  }

#pragma unroll
  for (int m = 0; m < 4; m++) {
    const long row0 = tM + wrow + m * 16 + g * 4;
#pragma unroll
    for (int n = 0; n < 4; n++) {
      const long col = tN + wcol + n * 16 + r;
      const float bb = bias[col];
      if (MODE == 0) {
#pragma unroll
        for (int q = 0; q < 4; q++)
          ((float*)C0)[(row0 + q) * N + col] = (acc[m][n][q] + bb) * scale;
      } else {  // MODE 3
        u16 vals[4];
#pragma unroll
        for (int q = 0; q < 4; q++) vals[q] = f2bf(acc[m][n][q] + bb);
        if (col < 2048) {
#pragma unroll
          for (int q = 0; q < 4; q++)
            ((u16*)C0)[(row0 + q) * 2048 + col] = vals[q];
        } else if (col < 2176) {
#pragma unroll
          for (int q = 0; q < 4; q++)
            ((u16*)C1)[(row0 + q) * 128 + (col - 2048)] = vals[q];
        } else {
          // V^T with per-64-tile k-linear permutation
          const long b2 = row0 >> 11;
          const long t0r = row0 & 2047;
          const int tl = (int)(t0r & 63);
          const int rbase = tl & 15, blk = tl >> 4;
          u16* vp = (u16*)C2 + (b2 * 128 + (col - 2176)) * 2048 + (t0r >> 6) * 64;
#pragma unroll
          for (int q = 0; q < 4; q++)
            vp[(rbase + q) * 4 + blk] = vals[q];
        }
      }
    }
  }
}

// ---------------- Flash attention, MQA ----------------
// R13 structure with the CU's two 4-wave blocks MERGED into one 8-wave block
// (512 thr, 256 q-rows, grid 256 = 1 block/CU): same waves/SIMD, same
// per-wave math/swizzles/softmax, but K/V staged ONCE per CU-tile instead of
// twice (the two co-resident blocks were staging identical (b) tiles).
// Staging DS-write traffic per unit work halves.
__global__ __launch_bounds__(512, 2)
void attn_mqa13(const u16* __restrict__ Q, const u16* __restrict__ Kb,
                const u16* __restrict__ VT, u16* __restrict__ O)
{
  constexpr int S = 2048;
  const int bid = blockIdx.x;
  const int qt = bid & 7;            // 8 q-tiles of 256 rows
  const int head = (bid >> 3) & 15;
  const int b = bid >> 7;
  const int tid = threadIdx.x;
  const int wave = tid >> 6, lane = tid & 63;  // wave 0..7
  const int g = lane >> 4, r = lane & 15;

  __shared__ u16 Ks[2][64 * 128];   // 32 KB
  __shared__ u16 VTs[2][128 * 64];  // 32 KB
  __shared__ u16 Ps[8][16 * 64];    // 16 KB  -> 80 KB total, 1 block/CU

  bf16x8 qf[2][4];
#pragma unroll
  for (int qb = 0; qb < 2; qb++) {
    const u16* qp = Q + (long)(b * S + qt * 256 + qb * 128 + wave * 16 + r) * 2048
                      + head * 128 + g * 8;
#pragma unroll
    for (int ks = 0; ks < 4; ks++) qf[qb][ks] = *(const bf16x8*)(qp + ks * 32);
  }

  f32x4 oacc[2][8] = {};
  float lsum[2][4] = {};
  char* psb = (char*)Ps[wave];

  auto stageK = [&](int buf, int t0) {
    char* dst = (char*)Ks[buf];
#pragma unroll
    for (int p = 0; p < 2; p++) {
      int D = p * 8192 + wave * 1024 + lane * 16;
      int row = D >> 8;
      int col2 = (D & 255) ^ ((row & 7) << 4);
      gload_lds16(Kb + ((long)b * S + t0 + row) * 128 + (col2 >> 1), dst + D);
    }
  };
  auto stageV = [&](int buf, int t0) {
    char* dst = (char*)VTs[buf];
#pragma unroll
    for (int p = 0; p < 2; p++) {
      int D = p * 8192 + wave * 1024 + lane * 16;
      int row = D >> 7;
      int colb = (D & 127) ^ ((row & 7) << 4);
      gload_lds16(VT + ((long)b * 128 + row) * 2048 + t0 + (colb >> 1), dst + D);
    }
  };

  stageK(0, 0);
  stageV(0, 0);
  __syncthreads();

  for (int t0 = 0; t0 < S; t0 += 64) {
    const int cur = (t0 >> 6) & 1;
    const bool nxt = (t0 + 64) < S;

    if (nxt) { stageK(cur ^ 1, t0 + 64); stageV(cur ^ 1, t0 + 64); }

    // QK^T from Ks[cur]
    char* Ks3 = (char*)Ks[cur];
    f32x4 st[2][4] = {};
    __builtin_amdgcn_s_setprio(1);
#pragma unroll
    for (int ks = 0; ks < 4; ks++) {
#pragma unroll
      for (int nf = 0; nf < 4; nf++) {
        const int trow = nf * 16 + r;
        const int col2 = (ks * 64 + g * 16) ^ ((trow & 7) << 4);
        bf16x8 kf = *(const bf16x8*)(Ks3 + trow * 256 + col2);
        st[0][nf] = __builtin_amdgcn_mfma_f32_16x16x32_bf16(qf[0][ks], kf, st[0][nf], 0, 0, 0);
        st[1][nf] = __builtin_amdgcn_mfma_f32_16x16x32_bf16(qf[1][ks], kf, st[1][nf], 0, 0, 0);
      }
    }
    __builtin_amdgcn_s_setprio(0);

    // softmax + PV per q-block; V frags cached qb0 -> qb1
    char* Vs3 = (char*)VTs[cur];
    bf16x8 vreg[2][8];
#pragma unroll
    for (int qb = 0; qb < 2; qb++) {
#pragma unroll
      for (int q = 0; q < 4; q++) {
        const int prow = g * 4 + q;
        u16 pk[4];
#pragma unroll
        for (int nf = 0; nf < 4; nf++) {
          float p = __builtin_amdgcn_exp2f(st[qb][nf][q]);
          lsum[qb][q] += p;
          pk[nf] = __builtin_bit_cast(u16, (__bf16)p);
        }
        *(ushort4*)(psb + prow * 128 + ((r * 8) ^ ((prow & 7) << 4))) =
            *(const ushort4*)pk;
      }
      __builtin_amdgcn_s_setprio(1);
#pragma unroll
      for (int ks = 0; ks < 2; ks++) {
        bf16x8 pf = *(const bf16x8*)(psb + r * 128 +
                                     ((ks * 64 + g * 16) ^ ((r & 7) << 4)));
#pragma unroll
        for (int dn = 0; dn < 8; dn++) {
          if (qb == 0) {
            const int d = dn * 16 + r;
            vreg[ks][dn] = *(const bf16x8*)(Vs3 + d * 128 +
                                            ((ks * 64 + g * 16) ^ ((d & 7) << 4)));
          }
          oacc[qb][dn] = __builtin_amdgcn_mfma_f32_16x16x32_bf16(pf, vreg[ks][dn],
                                                                 oacc[qb][dn], 0, 0, 0);
        }
      }
      __builtin_amdgcn_s_setprio(0);
    }

    __syncthreads();
  }

#pragma unroll
  for (int off = 1; off < 16; off <<= 1)
#pragma unroll
    for (int qb = 0; qb < 2; qb++)
#pragma unroll
      for (int q = 0; q < 4; q++)
        lsum[qb][q] += __shfl_xor(lsum[qb][q], off);

#pragma unroll
  for (int qb = 0; qb < 2; qb++) {
#pragma unroll
    for (int q = 0; q < 4; q++) {
      const float inv = 1.f / lsum[qb][q];
      const long orow = (long)(b * S + qt * 256 + qb * 128 + wave * 16 + g * 4 + q);
#pragma unroll
      for (int dn = 0; dn < 8; dn++)
        O[orow * 2048 + head * 128 + dn * 16 + r] = f2bf(oacc[qb][dn][q] * inv);
    }
  }
}

// ---------------- launch ----------------
extern "C" void kernel_launch(void* const* d_in, const int* in_sizes, int n_in,
                              void* d_out, int out_size, void* d_ws, size_t ws_size,
                              hipStream_t stream) {
  const float* x  = (const float*)d_in[0];
  const float* Wq = (const float*)d_in[1];
  const float* bq = (const float*)d_in[2];
  const float* Wk = (const float*)d_in[3];
  const float* bk = (const float*)d_in[4];
  const float* Wv = (const float*)d_in[5];
  const float* bv = (const float*)d_in[6];
  const float* Wo = (const float*)d_in[7];
  const float* bo = (const float*)d_in[8];
  float* out = (float*)d_out;

  char* ws = (char*)d_ws;
  u16* x_bf     = (u16*)(ws + (0ul  << 20));  // 16 MiB
  u16* q_bf     = (u16*)(ws + (16ul << 20));  // 16 MiB
  u16* wqkv_bf  = (u16*)(ws + (32ul << 20));  // 9 MiB  [2304][2048]
  u16* wo_bf    = (u16*)(ws + (42ul << 20));  // 8 MiB
  u16* k_bf     = (u16*)(ws + (50ul << 20));  // 1 MiB  K   [b*S][128]
  u16* vt_bf    = (u16*)(ws + (51ul << 20));  // 1 MiB  V^T [b*128][2048] k_lin-permuted
  u16* attn_bf  = (u16*)(ws + (52ul << 20));  // 16 MiB
  float* bias_a = (float*)(ws + (68ul << 20));

  const float QS = 0.12751744f;  // log2(e)/sqrt(128)

  cvt_all<<<8457, 256, 0, stream>>>(x, Wq, Wk, Wv, Wo, bq, bk, bv,
                                    x_bf, wqkv_bf, wo_bf, bias_a, QS);

  // fused QKV projection: [4096,2304]; Q scaled via weights, K/V^T routed
  gemm_bt<3><<<dim3(18, 32), 256, 0, stream>>>(
      x_bf, wqkv_bf, bias_a, q_bf, k_bf, vt_bf, 4096, 2304, 2048, 1.0f);
  // attention -> [4096, 2048] bf16 (8-wave blocks, shared staging)
  attn_mqa13<<<256, 512, 0, stream>>>(q_bf, k_bf, vt_bf, attn_bf);
  // out = attn Wo^T + bo  (fp32)
  gemm_bt<0><<<dim3(16, 32), 256, 0, stream>>>(
      attn_bf, wo_bf, bo, out, nullptr, nullptr, 4096, 2048, 2048, 1.0f);
}